// Round 9
// baseline (97.765 us; speedup 1.0000x reference)
//
#include <hip/hip_runtime.h>
#include <hip/hip_bf16.h>

// Problem constants
#define NF 40   // fields f
#define NI 40   // in_sub i
#define NN 40   // out_sub n
#define ED 64   // embed D, d
#define NB 256  // batch b

typedef __attribute__((ext_vector_type(8))) short   short8;
typedef __attribute__((ext_vector_type(8))) __bf16  bf16x8;
typedef __attribute__((ext_vector_type(4))) float   f32x4;

__device__ __forceinline__ unsigned short f2bf(float x) {
    union { float f; unsigned u; } v; v.f = x;
    unsigned r = v.u + 0x7FFFu + ((v.u >> 16) & 1u);   // RNE
    return (unsigned short)(r >> 16);
}

__device__ __forceinline__ bf16x8 ld_frag(const unsigned short* p) {
    return __builtin_bit_cast(bf16x8, *(const short8*)p);
}

__device__ __forceinline__ f32x4 mfma16(bf16x8 a, bf16x8 b, f32x4 c) {
    return __builtin_amdgcn_mfma_f32_16x16x32_bf16(a, b, c, 0, 0, 0);
}

// ==========================================================================
// FAST PATH: prep4 (params only, verified R5) + main6.
//   whp[n][D(64)][d(64)] = W[n][D][d]*h[n][d]   (bf16, fragment-ready)
//   alp[n][i(48)][f(64)] = alpha[f][i][n]       (pads -> 0)
// ==========================================================================
#define WHP_N (64 * 64)   // 4096
#define ALP_N (48 * 64)   // 3072

// Prep: 80 blocks x 256 thr (verified in R5).
__global__ __launch_bounds__(256) void gif_prep4(
        const float* __restrict__ W, const float* __restrict__ alpha,
        const float* __restrict__ h,
        unsigned short* __restrict__ whp, unsigned short* __restrict__ alp) {
    const int x = blockIdx.x;
    const int t = threadIdx.x;
    if (x < NN) {
        const int n = x;
        for (int idx = t; idx < 64 * 64; idx += 256) {       // whp coalesced
            int d = idx & 63;
            whp[n * WHP_N + idx] = f2bf(W[n * ED * ED + idx] * h[n * ED + d]);
        }
        for (int idx = t; idx < 8 * 64; idx += 256)          // rows i 40..47
            alp[n * ALP_N + (40 + (idx >> 6)) * 64 + (idx & 63)] = 0;
        for (int idx = t; idx < 40 * 24; idx += 256) {       // cols f 40..63
            int i = idx / 24, f = 40 + idx - i * 24;
            alp[n * ALP_N + i * 64 + f] = 0;
        }
    } else {
        const int f = x - NN;
        for (int idx = t; idx < NI * NN; idx += 256) {       // coalesced read
            int i = idx / NN, n = idx - i * NN;
            alp[n * ALP_N + i * 64 + f] = f2bf(alpha[(f * NI + i) * NN + n]);
        }
    }
}

// Main: grid (64, 10) x 256 thr (4 waves). Block = (4 b's, 4 n's).
// Wave w owns n = ng*4+w: 14 one-time b128 param gathers (16 segs each),
// held in registers for the whole kernel. b-loop (4 iters): R5/R8-proven
// in-block fp32->bf16 LDS staging of Bi[b]/B0[b]^T, 48 MFMAs,
// shuffle-reduce, store. LDS = 16128 B -> 3 blocks/CU.
#define PSM 72
__global__ __launch_bounds__(256, 3) void gif_main6(
        const float* __restrict__ B0, const float* __restrict__ Bi,
        const unsigned short* __restrict__ whp,
        const unsigned short* __restrict__ alp,
        float* __restrict__ out) {
    const int bg = blockIdx.x;         // 0..63 : b in [bg*4, bg*4+4)
    const int ng = blockIdx.y;         // 0..9  : n in [ng*4, ng*4+4)
    const int t = threadIdx.x;
    const int lane = t & 63, w = t >> 6;
    const int quad = lane >> 4, l15 = lane & 15, fo = quad * 8;
    const int n = ng * 4 + w;

    __shared__ __align__(16) unsigned short sBi[48 * PSM];  // [i][d]  6912 B
    __shared__ __align__(16) unsigned short sBT[64 * PSM];  // [D][f]  9216 B

    // ---- one-time: this wave's n-params into registers (14 gathers) ----
    bf16x8 alA[3][2], whB[4][2];
    {
        const unsigned short* ap = alp + n * ALP_N;
        const unsigned short* wp = whp + n * WHP_N;
#pragma unroll
        for (int m = 0; m < 3; ++m)
#pragma unroll
            for (int s = 0; s < 2; ++s)
                alA[m][s] = ld_frag(&ap[(m * 16 + l15) * 64 + s * 32 + fo]);
#pragma unroll
        for (int tt = 0; tt < 4; ++tt)
#pragma unroll
            for (int s = 0; s < 2; ++s)
                whB[tt][s] = ld_frag(&wp[(tt * 16 + l15) * 64 + s * 32 + fo]);
    }

    // ---- b-loop ----
    for (int j = 0; j < 4; ++j) {
        const int b = bg * 4 + j;
        if (j) __syncthreads();   // previous iteration's LDS reads done

        // stage Bi[b] and B0[b]^T into LDS (coalesced global reads)
        const float* bi = Bi + (size_t)b * NI * ED;
        const float* b0 = B0 + (size_t)b * NF * ED;
        for (int idx = t; idx < NI * ED; idx += 256) {
            int i = idx >> 6, d = idx & 63;
            sBi[i * PSM + d] = f2bf(bi[idx]);
        }
        for (int idx = t; idx < 8 * 64; idx += 256)          // pad rows i 40..47
            sBi[(40 + (idx >> 6)) * PSM + (idx & 63)] = 0;
        for (int idx = t; idx < NF * ED; idx += 256) {       // transpose write
            int f = idx >> 6, D = idx & 63;
            sBT[D * PSM + f] = f2bf(b0[idx]);
        }
        for (int idx = t; idx < 64 * 24; idx += 256) {       // pad cols f 40..63
            int D = idx / 24, f = 40 + idx - D * 24;
            sBT[D * PSM + f] = 0;
        }
        __syncthreads();

        bf16x8 biA[3][2];
#pragma unroll
        for (int m = 0; m < 3; ++m)
#pragma unroll
            for (int s = 0; s < 2; ++s)
                biA[m][s] = ld_frag(&sBi[(m * 16 + l15) * PSM + s * 32 + fo]);

        float p[4];
#pragma unroll
        for (int tt = 0; tt < 4; ++tt) {
            bf16x8 bb0 = ld_frag(&sBT[(tt * 16 + l15) * PSM + fo]);
            bf16x8 bb1 = ld_frag(&sBT[(tt * 16 + l15) * PSM + 32 + fo]);
            float acc = 0.f;
#pragma unroll
            for (int m = 0; m < 3; ++m) {
                f32x4 z = {0.f, 0.f, 0.f, 0.f};
                f32x4 T = mfma16(biA[m][0], whB[tt][0], z);
                T = mfma16(biA[m][1], whB[tt][1], T);
                f32x4 G = mfma16(alA[m][0], bb0, z);
                G = mfma16(alA[m][1], bb1, G);
                acc += T[0] * G[0] + T[1] * G[1] + T[2] * G[2] + T[3] * G[3];
            }
            p[tt] = acc;
        }
#pragma unroll
        for (int tt = 0; tt < 4; ++tt) {
            p[tt] += __shfl_xor(p[tt], 16, 64);
            p[tt] += __shfl_xor(p[tt], 32, 64);
        }
        float v = (quad == 0) ? p[0] : (quad == 1) ? p[1] : (quad == 2) ? p[2] : p[3];
        out[((size_t)b * NN + n) * ED + lane] = v;
    }
}

// ==========================================================================
// FALLBACK (small ws): round-2 verified kernels.
// ==========================================================================
#define PS 72
#define WH_N (ED * PS)
#define AL_N (48 * PS)

__global__ __launch_bounds__(256) void gif_prep(
        const float* __restrict__ W, const float* __restrict__ alpha,
        const float* __restrict__ h,
        unsigned short* __restrict__ whp, unsigned short* __restrict__ alp) {
    const int n = blockIdx.x;
    const int t0 = blockIdx.y * 256 + threadIdx.x;
    for (int idx = t0; idx < ED * PS; idx += 1024) {
        int D = idx / PS, c = idx - D * PS;
        float v = (c < ED) ? W[n * ED * ED + D * ED + c] * h[n * ED + c] : 0.f;
        whp[n * WH_N + idx] = f2bf(v);
    }
    for (int idx = t0; idx < 48 * PS; idx += 1024) {
        int i = idx / PS, c = idx - i * PS;
        float v = (i < NI && c < NF) ? alpha[(c * NI + i) * NN + n] : 0.f;
        alp[n * AL_N + idx] = f2bf(v);
    }
}

__device__ __forceinline__ bf16x8 mk_al_frag(const float* __restrict__ alpha,
        int n, int m, int s, int l15, int quad) {
    bf16x8 r;
    const int row = m * 16 + l15;
    const int f0 = s * 32 + quad * 8;
#pragma unroll
    for (int j = 0; j < 8; ++j) {
        const int f = f0 + j;
        float v = (row < NI && f < NF) ? alpha[(f * NI + row) * NN + n] : 0.f;
        r[j] = (__bf16)v;
    }
    return r;
}
__device__ __forceinline__ bf16x8 mk_wh_frag(const float* __restrict__ W,
        const float* __restrict__ h, int n, int tt, int s, int l15, int quad) {
    bf16x8 r;
    const int row = tt * 16 + l15;
    const int k0 = s * 32 + quad * 8;
#pragma unroll
    for (int j = 0; j < 8; ++j) {
        float v = W[n * ED * ED + row * ED + k0 + j] * h[n * ED + k0 + j];
        r[j] = (__bf16)v;
    }
    return r;
}

__global__ __launch_bounds__(256) void gif_mfma(
        const float* __restrict__ B0, const float* __restrict__ Bi,
        const unsigned short* __restrict__ whp, const unsigned short* __restrict__ alp,
        const float* __restrict__ W, const float* __restrict__ alpha,
        const float* __restrict__ h, int useWs, float* __restrict__ out) {
    const int q = blockIdx.x >> 8;
    const int b = blockIdx.x & 255;

    __shared__ __align__(16) unsigned short sBi[48 * PS];
    __shared__ __align__(16) unsigned short sBT[ED * PS];

    const int t = threadIdx.x;
    for (int idx = t; idx < 48 * PS; idx += 256) {
        int i = idx / PS, c = idx - i * PS;
        sBi[idx] = (i < NI && c < ED) ? f2bf(Bi[b * NI * ED + i * ED + c])
                                      : (unsigned short)0;
    }
    for (int idx = t; idx < ED * PS; idx += 256) {
        int D = idx / PS, c = idx - D * PS;
        sBT[idx] = (c < NF) ? f2bf(B0[b * NF * ED + c * ED + D])
                            : (unsigned short)0;
    }
    __syncthreads();

    const int lane = t & 63, w = t >> 6;
    const int quad = lane >> 4, l15 = lane & 15;
    const int fragoff = quad * 8;

    bf16x8 biA[3][2], b0B[4][2];
#pragma unroll
    for (int m = 0; m < 3; ++m)
#pragma unroll
        for (int s = 0; s < 2; ++s)
            biA[m][s] = ld_frag(&sBi[(m * 16 + l15) * PS + s * 32 + fragoff]);
#pragma unroll
    for (int tt = 0; tt < 4; ++tt)
#pragma unroll
        for (int s = 0; s < 2; ++s)
            b0B[tt][s] = ld_frag(&sBT[(tt * 16 + l15) * PS + s * 32 + fragoff]);

#pragma unroll
    for (int rep = 0; rep < 2; ++rep) {
        const int n = q * 8 + w + rep * 4;

        bf16x8 alA[3][2];
        if (useWs) {
#pragma unroll
            for (int m = 0; m < 3; ++m)
#pragma unroll
                for (int s = 0; s < 2; ++s)
                    alA[m][s] = ld_frag(&alp[n * AL_N + (m * 16 + l15) * PS + s * 32 + fragoff]);
        } else {
#pragma unroll
            for (int m = 0; m < 3; ++m)
#pragma unroll
                for (int s = 0; s < 2; ++s)
                    alA[m][s] = mk_al_frag(alpha, n, m, s, l15, quad);
        }

        float p[4];
#pragma unroll
        for (int tt = 0; tt < 4; ++tt) {
            bf16x8 whB2[2];
            if (useWs) {
                const unsigned short* wpp = &whp[n * WH_N + (tt * 16 + l15) * PS + fragoff];
                whB2[0] = ld_frag(wpp);
                whB2[1] = ld_frag(wpp + 32);
            } else {
                whB2[0] = mk_wh_frag(W, h, n, tt, 0, l15, quad);
                whB2[1] = mk_wh_frag(W, h, n, tt, 1, l15, quad);
            }
            float acc = 0.f;
#pragma unroll
            for (int m = 0; m < 3; ++m) {
                f32x4 z = {0.f, 0.f, 0.f, 0.f};
                f32x4 T = mfma16(biA[m][0], whB2[0], z);
                T = mfma16(biA[m][1], whB2[1], T);
                f32x4 G = mfma16(alA[m][0], b0B[tt][0], z);
                G = mfma16(alA[m][1], b0B[tt][1], G);
                acc += T[0] * G[0] + T[1] * G[1] + T[2] * G[2] + T[3] * G[3];
            }
            p[tt] = acc;
        }
#pragma unroll
        for (int tt = 0; tt < 4; ++tt) {
            p[tt] += __shfl_xor(p[tt], 16, 64);
            p[tt] += __shfl_xor(p[tt], 32, 64);
        }
        float v = (quad == 0) ? p[0] : (quad == 1) ? p[1] : (quad == 2) ? p[2] : p[3];
        out[(b * NN + n) * ED + lane] = v;
    }
}

// ==========================================================================
extern "C" void kernel_launch(void* const* d_in, const int* in_sizes, int n_in,
                              void* d_out, int out_size, void* d_ws, size_t ws_size,
                              hipStream_t stream) {
    const float* B0    = (const float*)d_in[0];  // (256,40,64)
    const float* Bi    = (const float*)d_in[1];  // (256,40,64)
    const float* W     = (const float*)d_in[2];  // (40,64,64)
    const float* alpha = (const float*)d_in[3];  // (40,40,40)
    const float* h     = (const float*)d_in[4];  // (40,64,1)
    float* out = (float*)d_out;                  // (256,40,64)

    const size_t need2 = (size_t)(NN * WHP_N + NN * ALP_N) * sizeof(unsigned short);
    if (ws_size >= need2) {
        unsigned short* whp = (unsigned short*)d_ws;
        unsigned short* alp = whp + (size_t)NN * WHP_N;
        gif_prep4<<<NN + NF, 256, 0, stream>>>(W, alpha, h, whp, alp);
        gif_main6<<<dim3(NB / 4, NN / 4), 256, 0, stream>>>(B0, Bi, whp, alp, out);
        return;
    }

    const size_t need1 = (size_t)(NN * WH_N + NN * AL_N) * sizeof(unsigned short);
    const int useWs = (ws_size >= need1) ? 1 : 0;
    unsigned short* whp = (unsigned short*)d_ws;
    unsigned short* alp = whp + (size_t)NN * WH_N;
    if (useWs) {
        gif_prep<<<dim3(NN, 4), 256, 0, stream>>>(W, alpha, h, whp, alp);
    }
    gif_mfma<<<5 * NB, 256, 0, stream>>>(B0, Bi, whp, alp, W, alpha, h, useWs, out);
}

// Round 10
// 84.412 us; speedup vs baseline: 1.1582x; 1.1582x over previous
//
#include <hip/hip_runtime.h>
#include <hip/hip_bf16.h>

// Problem constants
#define NF 40   // fields f
#define NI 40   // in_sub i
#define NN 40   // out_sub n
#define ED 64   // embed D, d
#define NB 256  // batch b

typedef __attribute__((ext_vector_type(8))) short   short8;
typedef __attribute__((ext_vector_type(8))) __bf16  bf16x8;
typedef __attribute__((ext_vector_type(4))) float   f32x4;

__device__ __forceinline__ unsigned short f2bf(float x) {
    union { float f; unsigned u; } v; v.f = x;
    unsigned r = v.u + 0x7FFFu + ((v.u >> 16) & 1u);   // RNE
    return (unsigned short)(r >> 16);
}

__device__ __forceinline__ bf16x8 ld_frag(const unsigned short* p) {
    return __builtin_bit_cast(bf16x8, *(const short8*)p);
}

__device__ __forceinline__ f32x4 mfma16(bf16x8 a, bf16x8 b, f32x4 c) {
    return __builtin_amdgcn_mfma_f32_16x16x32_bf16(a, b, c, 0, 0, 0);
}

// ==========================================================================
// FAST PATH: prep4 (params only, verified R5/R9) + main7 (main4 + hoisted
// staging loads).
//   whp[n][D(64)][d(64)] = W[n][D][d]*h[n][d]   (bf16, fragment-ready)
//   alp[n][i(48)][f(64)] = alpha[f][i][n]       (pads -> 0)
// ==========================================================================
#define WHP_N (64 * 64)   // 4096
#define ALP_N (48 * 64)   // 3072

// Prep: 80 blocks x 256 thr (byte-identical to verified R5 version).
__global__ __launch_bounds__(256) void gif_prep4(
        const float* __restrict__ W, const float* __restrict__ alpha,
        const float* __restrict__ h,
        unsigned short* __restrict__ whp, unsigned short* __restrict__ alp) {
    const int x = blockIdx.x;
    const int t = threadIdx.x;
    if (x < NN) {
        const int n = x;
        for (int idx = t; idx < 64 * 64; idx += 256) {       // whp coalesced
            int d = idx & 63;
            whp[n * WHP_N + idx] = f2bf(W[n * ED * ED + idx] * h[n * ED + d]);
        }
        for (int idx = t; idx < 8 * 64; idx += 256)          // rows i 40..47
            alp[n * ALP_N + (40 + (idx >> 6)) * 64 + (idx & 63)] = 0;
        for (int idx = t; idx < 40 * 24; idx += 256) {       // cols f 40..63
            int i = idx / 24, f = 40 + idx - i * 24;
            alp[n * ALP_N + i * 64 + f] = 0;
        }
    } else {
        const int f = x - NN;
        for (int idx = t; idx < NI * NN; idx += 256) {       // coalesced read
            int i = idx / NN, n = idx - i * NN;
            alp[n * ALP_N + i * 64 + f] = f2bf(alpha[(f * NI + i) * NN + n]);
        }
    }
}

// Main: 512 blocks x 256 thr (4 waves), 2 blocks/CU — R5's main4 with ONE
// change: the per-b staging loads (6 float4/thread) are issued FIRST so
// their latency overlaps the 28 param-gather b128s; conversion + LDS writes
// happen after the gathers are in flight. n-loop is byte-identical to main4.
#define PSM 72
__global__ __launch_bounds__(256, 2) void gif_main7(
        const float* __restrict__ B0, const float* __restrict__ Bi,
        const unsigned short* __restrict__ whp,
        const unsigned short* __restrict__ alp,
        float* __restrict__ out) {
    const int q = blockIdx.x >> 8;
    const int b = blockIdx.x & 255;
    const int t = threadIdx.x;
    const int lane = t & 63, w = t >> 6;
    const int quad = lane >> 4, l15 = lane & 15, fo = quad * 8;

    __shared__ __align__(16) unsigned short sBi[48 * PSM];  // [i][d]  6912 B
    __shared__ __align__(16) unsigned short sBT[64 * PSM];  // [D][f]  9216 B

    // ---- 1. staging loads issued FIRST (coalesced float4, kept in regs) ----
    const float4* biv = (const float4*)(Bi + (size_t)b * NI * ED);  // 640 vec4
    const float4* b0v = (const float4*)(B0 + (size_t)b * NF * ED);  // 640 vec4
    float4 rbi[3], rb0[3];
#pragma unroll
    for (int k = 0; k < 3; ++k) {
        const int c = t + k * 256;
        if (c < 640) { rbi[k] = biv[c]; rb0[k] = b0v[c]; }
    }

    // ---- 2. first n's param fragments (28 b128 gathers, overlap above) ----
    bf16x8 alA[2][3][2], whB[2][4][2];
    {
        const int n0 = q * 20 + w;
        const unsigned short* ap = alp + n0 * ALP_N;
        const unsigned short* wp = whp + n0 * WHP_N;
#pragma unroll
        for (int m = 0; m < 3; ++m)
#pragma unroll
            for (int s = 0; s < 2; ++s)
                alA[0][m][s] = ld_frag(&ap[(m * 16 + l15) * 64 + s * 32 + fo]);
#pragma unroll
        for (int tt = 0; tt < 4; ++tt)
#pragma unroll
            for (int s = 0; s < 2; ++s)
                whB[0][tt][s] = ld_frag(&wp[(tt * 16 + l15) * 64 + s * 32 + fo]);
    }

    // ---- 3. convert + write staging to LDS ----
#pragma unroll
    for (int k = 0; k < 3; ++k) {
        const int c = t + k * 256;
        if (c < 640) {
            const int r = c >> 4, col = (c & 15) * 4;   // row, 4-elem col base
            ushort4 pk;
            pk.x = f2bf(rbi[k].x); pk.y = f2bf(rbi[k].y);
            pk.z = f2bf(rbi[k].z); pk.w = f2bf(rbi[k].w);
            *(ushort4*)&sBi[r * PSM + col] = pk;        // [i][d], 8B store
            sBT[(col + 0) * PSM + r] = f2bf(rb0[k].x);  // transpose [D][f]
            sBT[(col + 1) * PSM + r] = f2bf(rb0[k].y);
            sBT[(col + 2) * PSM + r] = f2bf(rb0[k].z);
            sBT[(col + 3) * PSM + r] = f2bf(rb0[k].w);
        }
    }
    for (int idx = t; idx < 8 * 64; idx += 256)          // pad rows i 40..47
        sBi[(40 + (idx >> 6)) * PSM + (idx & 63)] = 0;
    for (int idx = t; idx < 64 * 24; idx += 256) {       // pad cols f 40..63
        int D = idx / 24, f = 40 + idx - D * 24;
        sBT[D * PSM + f] = 0;
    }
    __syncthreads();

    // ---- per-b fragments from LDS (ds_read_b128) ----
    bf16x8 biA[3][2], b0B[4][2];
#pragma unroll
    for (int m = 0; m < 3; ++m)
#pragma unroll
        for (int s = 0; s < 2; ++s)
            biA[m][s] = ld_frag(&sBi[(m * 16 + l15) * PSM + s * 32 + fo]);
#pragma unroll
    for (int tt = 0; tt < 4; ++tt)
#pragma unroll
        for (int s = 0; s < 2; ++s)
            b0B[tt][s] = ld_frag(&sBT[(tt * 16 + l15) * PSM + s * 32 + fo]);

#pragma unroll
    for (int it = 0; it < 5; ++it) {
        const int cur = it & 1, nxt = cur ^ 1;
        const int n = q * 20 + it * 4 + w;

        if (it < 4) {   // prefetch next n's fragments (hidden by MFMA body)
            const unsigned short* ap = alp + (n + 4) * ALP_N;
            const unsigned short* wp = whp + (n + 4) * WHP_N;
#pragma unroll
            for (int m = 0; m < 3; ++m)
#pragma unroll
                for (int s = 0; s < 2; ++s)
                    alA[nxt][m][s] = ld_frag(&ap[(m * 16 + l15) * 64 + s * 32 + fo]);
#pragma unroll
            for (int tt = 0; tt < 4; ++tt)
#pragma unroll
                for (int s = 0; s < 2; ++s)
                    whB[nxt][tt][s] = ld_frag(&wp[(tt * 16 + l15) * 64 + s * 32 + fo]);
        }

        float p[4];
#pragma unroll
        for (int tt = 0; tt < 4; ++tt) {
            float acc = 0.f;
#pragma unroll
            for (int m = 0; m < 3; ++m) {
                f32x4 z = {0.f, 0.f, 0.f, 0.f};
                f32x4 T = mfma16(biA[m][0], whB[cur][tt][0], z);
                T = mfma16(biA[m][1], whB[cur][tt][1], T);
                f32x4 G = mfma16(alA[cur][m][0], b0B[tt][0], z);
                G = mfma16(alA[cur][m][1], b0B[tt][1], G);
                acc += T[0] * G[0] + T[1] * G[1] + T[2] * G[2] + T[3] * G[3];
            }
            p[tt] = acc;
        }
#pragma unroll
        for (int tt = 0; tt < 4; ++tt) {
            p[tt] += __shfl_xor(p[tt], 16, 64);
            p[tt] += __shfl_xor(p[tt], 32, 64);
        }
        float v = (quad == 0) ? p[0] : (quad == 1) ? p[1] : (quad == 2) ? p[2] : p[3];
        out[((size_t)b * NN + n) * ED + lane] = v;
    }
}

// ==========================================================================
// FALLBACK (small ws): round-2 verified kernels.
// ==========================================================================
#define PS 72
#define WH_N (ED * PS)
#define AL_N (48 * PS)

__global__ __launch_bounds__(256) void gif_prep(
        const float* __restrict__ W, const float* __restrict__ alpha,
        const float* __restrict__ h,
        unsigned short* __restrict__ whp, unsigned short* __restrict__ alp) {
    const int n = blockIdx.x;
    const int t0 = blockIdx.y * 256 + threadIdx.x;
    for (int idx = t0; idx < ED * PS; idx += 1024) {
        int D = idx / PS, c = idx - D * PS;
        float v = (c < ED) ? W[n * ED * ED + D * ED + c] * h[n * ED + c] : 0.f;
        whp[n * WH_N + idx] = f2bf(v);
    }
    for (int idx = t0; idx < 48 * PS; idx += 1024) {
        int i = idx / PS, c = idx - i * PS;
        float v = (i < NI && c < NF) ? alpha[(c * NI + i) * NN + n] : 0.f;
        alp[n * AL_N + idx] = f2bf(v);
    }
}

__device__ __forceinline__ bf16x8 mk_al_frag(const float* __restrict__ alpha,
        int n, int m, int s, int l15, int quad) {
    bf16x8 r;
    const int row = m * 16 + l15;
    const int f0 = s * 32 + quad * 8;
#pragma unroll
    for (int j = 0; j < 8; ++j) {
        const int f = f0 + j;
        float v = (row < NI && f < NF) ? alpha[(f * NI + row) * NN + n] : 0.f;
        r[j] = (__bf16)v;
    }
    return r;
}
__device__ __forceinline__ bf16x8 mk_wh_frag(const float* __restrict__ W,
        const float* __restrict__ h, int n, int tt, int s, int l15, int quad) {
    bf16x8 r;
    const int row = tt * 16 + l15;
    const int k0 = s * 32 + quad * 8;
#pragma unroll
    for (int j = 0; j < 8; ++j) {
        float v = W[n * ED * ED + row * ED + k0 + j] * h[n * ED + k0 + j];
        r[j] = (__bf16)v;
    }
    return r;
}

__global__ __launch_bounds__(256) void gif_mfma(
        const float* __restrict__ B0, const float* __restrict__ Bi,
        const unsigned short* __restrict__ whp, const unsigned short* __restrict__ alp,
        const float* __restrict__ W, const float* __restrict__ alpha,
        const float* __restrict__ h, int useWs, float* __restrict__ out) {
    const int q = blockIdx.x >> 8;
    const int b = blockIdx.x & 255;

    __shared__ __align__(16) unsigned short sBi[48 * PS];
    __shared__ __align__(16) unsigned short sBT[ED * PS];

    const int t = threadIdx.x;
    for (int idx = t; idx < 48 * PS; idx += 256) {
        int i = idx / PS, c = idx - i * PS;
        sBi[idx] = (i < NI && c < ED) ? f2bf(Bi[b * NI * ED + i * ED + c])
                                      : (unsigned short)0;
    }
    for (int idx = t; idx < ED * PS; idx += 256) {
        int D = idx / PS, c = idx - D * PS;
        sBT[idx] = (c < NF) ? f2bf(B0[b * NF * ED + c * ED + D])
                            : (unsigned short)0;
    }
    __syncthreads();

    const int lane = t & 63, w = t >> 6;
    const int quad = lane >> 4, l15 = lane & 15;
    const int fragoff = quad * 8;

    bf16x8 biA[3][2], b0B[4][2];
#pragma unroll
    for (int m = 0; m < 3; ++m)
#pragma unroll
        for (int s = 0; s < 2; ++s)
            biA[m][s] = ld_frag(&sBi[(m * 16 + l15) * PS + s * 32 + fragoff]);
#pragma unroll
    for (int tt = 0; tt < 4; ++tt)
#pragma unroll
        for (int s = 0; s < 2; ++s)
            b0B[tt][s] = ld_frag(&sBT[(tt * 16 + l15) * PS + s * 32 + fragoff]);

#pragma unroll
    for (int rep = 0; rep < 2; ++rep) {
        const int n = q * 8 + w + rep * 4;

        bf16x8 alA[3][2];
        if (useWs) {
#pragma unroll
            for (int m = 0; m < 3; ++m)
#pragma unroll
                for (int s = 0; s < 2; ++s)
                    alA[m][s] = ld_frag(&alp[n * AL_N + (m * 16 + l15) * PS + s * 32 + fragoff]);
        } else {
#pragma unroll
            for (int m = 0; m < 3; ++m)
#pragma unroll
                for (int s = 0; s < 2; ++s)
                    alA[m][s] = mk_al_frag(alpha, n, m, s, l15, quad);
        }

        float p[4];
#pragma unroll
        for (int tt = 0; tt < 4; ++tt) {
            bf16x8 whB2[2];
            if (useWs) {
                const unsigned short* wpp = &whp[n * WH_N + (tt * 16 + l15) * PS + fragoff];
                whB2[0] = ld_frag(wpp);
                whB2[1] = ld_frag(wpp + 32);
            } else {
                whB2[0] = mk_wh_frag(W, h, n, tt, 0, l15, quad);
                whB2[1] = mk_wh_frag(W, h, n, tt, 1, l15, quad);
            }
            float acc = 0.f;
#pragma unroll
            for (int m = 0; m < 3; ++m) {
                f32x4 z = {0.f, 0.f, 0.f, 0.f};
                f32x4 T = mfma16(biA[m][0], whB2[0], z);
                T = mfma16(biA[m][1], whB2[1], T);
                f32x4 G = mfma16(alA[m][0], b0B[tt][0], z);
                G = mfma16(alA[m][1], b0B[tt][1], G);
                acc += T[0] * G[0] + T[1] * G[1] + T[2] * G[2] + T[3] * G[3];
            }
            p[tt] = acc;
        }
#pragma unroll
        for (int tt = 0; tt < 4; ++tt) {
            p[tt] += __shfl_xor(p[tt], 16, 64);
            p[tt] += __shfl_xor(p[tt], 32, 64);
        }
        float v = (quad == 0) ? p[0] : (quad == 1) ? p[1] : (quad == 2) ? p[2] : p[3];
        out[(b * NN + n) * ED + lane] = v;
    }
}

// ==========================================================================
extern "C" void kernel_launch(void* const* d_in, const int* in_sizes, int n_in,
                              void* d_out, int out_size, void* d_ws, size_t ws_size,
                              hipStream_t stream) {
    const float* B0    = (const float*)d_in[0];  // (256,40,64)
    const float* Bi    = (const float*)d_in[1];  // (256,40,64)
    const float* W     = (const float*)d_in[2];  // (40,64,64)
    const float* alpha = (const float*)d_in[3];  // (40,40,40)
    const float* h     = (const float*)d_in[4];  // (40,64,1)
    float* out = (float*)d_out;                  // (256,40,64)

    const size_t need2 = (size_t)(NN * WHP_N + NN * ALP_N) * sizeof(unsigned short);
    if (ws_size >= need2) {
        unsigned short* whp = (unsigned short*)d_ws;
        unsigned short* alp = whp + (size_t)NN * WHP_N;
        gif_prep4<<<NN + NF, 256, 0, stream>>>(W, alpha, h, whp, alp);
        gif_main7<<<2 * NB, 256, 0, stream>>>(B0, Bi, whp, alp, out);
        return;
    }

    const size_t need1 = (size_t)(NN * WH_N + NN * AL_N) * sizeof(unsigned short);
    const int useWs = (ws_size >= need1) ? 1 : 0;
    unsigned short* whp = (unsigned short*)d_ws;
    unsigned short* alp = whp + (size_t)NN * WH_N;
    if (useWs) {
        gif_prep<<<dim3(NN, 4), 256, 0, stream>>>(W, alpha, h, whp, alp);
    }
    gif_mfma<<<5 * NB, 256, 0, stream>>>(B0, Bi, whp, alp, W, alpha, h, useWs, out);
}

// Round 11
// 81.526 us; speedup vs baseline: 1.1992x; 1.0354x over previous
//
#include <hip/hip_runtime.h>
#include <hip/hip_bf16.h>

// Problem constants
#define NF 40   // fields f
#define NI 40   // in_sub i
#define NN 40   // out_sub n
#define ED 64   // embed D, d
#define NB 256  // batch b

typedef __attribute__((ext_vector_type(8))) short   short8;
typedef __attribute__((ext_vector_type(8))) __bf16  bf16x8;
typedef __attribute__((ext_vector_type(4))) float   f32x4;

__device__ __forceinline__ unsigned short f2bf(float x) {
    union { float f; unsigned u; } v; v.f = x;
    unsigned r = v.u + 0x7FFFu + ((v.u >> 16) & 1u);   // RNE
    return (unsigned short)(r >> 16);
}

__device__ __forceinline__ bf16x8 ld_frag(const unsigned short* p) {
    return __builtin_bit_cast(bf16x8, *(const short8*)p);
}

__device__ __forceinline__ f32x4 mfma16(bf16x8 a, bf16x8 b, f32x4 c) {
    return __builtin_amdgcn_mfma_f32_16x16x32_bf16(a, b, c, 0, 0, 0);
}

// ==========================================================================
// FAST PATH: prep4 (params, verified R5/R9/R10) + main8.
//   whp[n][D(64)][d(64)] = W[n][D][d]*h[n][d]   (bf16, fragment-ready)
//   alp[n][i(48)][f(64)] = alpha[f][i][n]       (pads -> 0)
// ==========================================================================
#define WHP_N (64 * 64)   // 4096
#define ALP_N (48 * 64)   // 3072

// Prep: 80 blocks x 256 thr (byte-identical to verified R5 version).
__global__ __launch_bounds__(256) void gif_prep4(
        const float* __restrict__ W, const float* __restrict__ alpha,
        const float* __restrict__ h,
        unsigned short* __restrict__ whp, unsigned short* __restrict__ alp) {
    const int x = blockIdx.x;
    const int t = threadIdx.x;
    if (x < NN) {
        const int n = x;
        for (int idx = t; idx < 64 * 64; idx += 256) {       // whp coalesced
            int d = idx & 63;
            whp[n * WHP_N + idx] = f2bf(W[n * ED * ED + idx] * h[n * ED + d]);
        }
        for (int idx = t; idx < 8 * 64; idx += 256)          // rows i 40..47
            alp[n * ALP_N + (40 + (idx >> 6)) * 64 + (idx & 63)] = 0;
        for (int idx = t; idx < 40 * 24; idx += 256) {       // cols f 40..63
            int i = idx / 24, f = 40 + idx - i * 24;
            alp[n * ALP_N + i * 64 + f] = 0;
        }
    } else {
        const int f = x - NN;
        for (int idx = t; idx < NI * NN; idx += 256) {       // coalesced read
            int i = idx / NN, n = idx - i * NN;
            alp[n * ALP_N + i * 64 + f] = f2bf(alpha[(f * NI + i) * NN + n]);
        }
    }
}

// Main8: grid (64, 10) x 256 thr (4 waves). Block = (4 b's, 4 n's).
// Wave w owns n = ng*4+w: its 14 param frags are loaded ONCE and live in
// registers for the whole kernel (param traffic 280 KB/block -> 56 KB).
// b-loop (4 iters) software-pipelines main7's verified staging: prefetch
// b+1's 6 float4 into registers during b's 48-MFMA body; convert + LDS
// write between two barriers. Pad zeroing done once in the prologue
// (iterations only overwrite real rows/cols). LDS 16128 B.
#define PSM 72
__global__ __launch_bounds__(256, 2) void gif_main8(
        const float* __restrict__ B0, const float* __restrict__ Bi,
        const unsigned short* __restrict__ whp,
        const unsigned short* __restrict__ alp,
        float* __restrict__ out) {
    const int bg = blockIdx.x;         // 0..63 : b in [bg*4, bg*4+4)
    const int ng = blockIdx.y;         // 0..9  : n in [ng*4, ng*4+4)
    const int t = threadIdx.x;
    const int lane = t & 63, w = t >> 6;
    const int quad = lane >> 4, l15 = lane & 15, fo = quad * 8;
    const int n = ng * 4 + w;

    __shared__ __align__(16) unsigned short sBi[48 * PSM];  // [i][d]  6912 B
    __shared__ __align__(16) unsigned short sBT[64 * PSM];  // [D][f]  9216 B

    // ---- 1. staging loads for first b issued FIRST (coalesced float4) ----
    float4 rbi[3], rb0[3];
    {
        const float4* biv = (const float4*)(Bi + (size_t)(bg * 4) * NI * ED);
        const float4* b0v = (const float4*)(B0 + (size_t)(bg * 4) * NF * ED);
#pragma unroll
        for (int k = 0; k < 3; ++k) {
            const int c = t + k * 256;
            if (c < 640) { rbi[k] = biv[c]; rb0[k] = b0v[c]; }
        }
    }

    // ---- 2. this wave's n-params: 14 b128 gathers, ONCE (overlap above) ----
    bf16x8 alA[3][2], whB[4][2];
    {
        const unsigned short* ap = alp + n * ALP_N;
        const unsigned short* wp = whp + n * WHP_N;
#pragma unroll
        for (int m = 0; m < 3; ++m)
#pragma unroll
            for (int s = 0; s < 2; ++s)
                alA[m][s] = ld_frag(&ap[(m * 16 + l15) * 64 + s * 32 + fo]);
#pragma unroll
        for (int tt = 0; tt < 4; ++tt)
#pragma unroll
            for (int s = 0; s < 2; ++s)
                whB[tt][s] = ld_frag(&wp[(tt * 16 + l15) * 64 + s * 32 + fo]);
    }

    // ---- 3. zero pads ONCE (never touched again) ----
    for (int idx = t; idx < 8 * 64; idx += 256)          // sBi rows i 40..47
        sBi[(40 + (idx >> 6)) * PSM + (idx & 63)] = 0;
    for (int idx = t; idx < 64 * 24; idx += 256) {       // sBT cols f 40..63
        int D = idx / 24, f = 40 + idx - D * 24;
        sBT[D * PSM + f] = 0;
    }

    // ---- 4. convert + write first b's staging ----
#pragma unroll
    for (int k = 0; k < 3; ++k) {
        const int c = t + k * 256;
        if (c < 640) {
            const int r = c >> 4, col = (c & 15) * 4;
            ushort4 pk;
            pk.x = f2bf(rbi[k].x); pk.y = f2bf(rbi[k].y);
            pk.z = f2bf(rbi[k].z); pk.w = f2bf(rbi[k].w);
            *(ushort4*)&sBi[r * PSM + col] = pk;
            sBT[(col + 0) * PSM + r] = f2bf(rb0[k].x);
            sBT[(col + 1) * PSM + r] = f2bf(rb0[k].y);
            sBT[(col + 2) * PSM + r] = f2bf(rb0[k].z);
            sBT[(col + 3) * PSM + r] = f2bf(rb0[k].w);
        }
    }
    __syncthreads();

    // ---- 5. b-loop ----
#pragma unroll
    for (int j = 0; j < 4; ++j) {
        const int b = bg * 4 + j;

        if (j < 3) {   // prefetch next b's staging into registers
            const float4* biv = (const float4*)(Bi + (size_t)(b + 1) * NI * ED);
            const float4* b0v = (const float4*)(B0 + (size_t)(b + 1) * NF * ED);
#pragma unroll
            for (int k = 0; k < 3; ++k) {
                const int c = t + k * 256;
                if (c < 640) { rbi[k] = biv[c]; rb0[k] = b0v[c]; }
            }
        }

        // per-b fragments from LDS + 48-MFMA body
        bf16x8 biA[3][2];
#pragma unroll
        for (int m = 0; m < 3; ++m)
#pragma unroll
            for (int s = 0; s < 2; ++s)
                biA[m][s] = ld_frag(&sBi[(m * 16 + l15) * PSM + s * 32 + fo]);

        float p[4];
#pragma unroll
        for (int tt = 0; tt < 4; ++tt) {
            bf16x8 bb0 = ld_frag(&sBT[(tt * 16 + l15) * PSM + fo]);
            bf16x8 bb1 = ld_frag(&sBT[(tt * 16 + l15) * PSM + 32 + fo]);
            float acc = 0.f;
#pragma unroll
            for (int m = 0; m < 3; ++m) {
                f32x4 z = {0.f, 0.f, 0.f, 0.f};
                f32x4 T = mfma16(biA[m][0], whB[tt][0], z);
                T = mfma16(biA[m][1], whB[tt][1], T);
                f32x4 G = mfma16(alA[m][0], bb0, z);
                G = mfma16(alA[m][1], bb1, G);
                acc += T[0] * G[0] + T[1] * G[1] + T[2] * G[2] + T[3] * G[3];
            }
            p[tt] = acc;
        }
#pragma unroll
        for (int tt = 0; tt < 4; ++tt) {
            p[tt] += __shfl_xor(p[tt], 16, 64);
            p[tt] += __shfl_xor(p[tt], 32, 64);
        }
        float v = (quad == 0) ? p[0] : (quad == 1) ? p[1] : (quad == 2) ? p[2] : p[3];
        out[((size_t)b * NN + n) * ED + lane] = v;

        if (j < 3) {   // restage for b+1 between two barriers
            __syncthreads();   // all waves done reading sBi/sBT
#pragma unroll
            for (int k = 0; k < 3; ++k) {
                const int c = t + k * 256;
                if (c < 640) {
                    const int r = c >> 4, col = (c & 15) * 4;
                    ushort4 pk;
                    pk.x = f2bf(rbi[k].x); pk.y = f2bf(rbi[k].y);
                    pk.z = f2bf(rbi[k].z); pk.w = f2bf(rbi[k].w);
                    *(ushort4*)&sBi[r * PSM + col] = pk;
                    sBT[(col + 0) * PSM + r] = f2bf(rb0[k].x);
                    sBT[(col + 1) * PSM + r] = f2bf(rb0[k].y);
                    sBT[(col + 2) * PSM + r] = f2bf(rb0[k].z);
                    sBT[(col + 3) * PSM + r] = f2bf(rb0[k].w);
                }
            }
            __syncthreads();   // staging visible
        }
    }
}

// ==========================================================================
// FALLBACK (small ws): round-2 verified kernels.
// ==========================================================================
#define PS 72
#define WH_N (ED * PS)
#define AL_N (48 * PS)

__global__ __launch_bounds__(256) void gif_prep(
        const float* __restrict__ W, const float* __restrict__ alpha,
        const float* __restrict__ h,
        unsigned short* __restrict__ whp, unsigned short* __restrict__ alp) {
    const int n = blockIdx.x;
    const int t0 = blockIdx.y * 256 + threadIdx.x;
    for (int idx = t0; idx < ED * PS; idx += 1024) {
        int D = idx / PS, c = idx - D * PS;
        float v = (c < ED) ? W[n * ED * ED + D * ED + c] * h[n * ED + c] : 0.f;
        whp[n * WH_N + idx] = f2bf(v);
    }
    for (int idx = t0; idx < 48 * PS; idx += 1024) {
        int i = idx / PS, c = idx - i * PS;
        float v = (i < NI && c < NF) ? alpha[(c * NI + i) * NN + n] : 0.f;
        alp[n * AL_N + idx] = f2bf(v);
    }
}

__device__ __forceinline__ bf16x8 mk_al_frag(const float* __restrict__ alpha,
        int n, int m, int s, int l15, int quad) {
    bf16x8 r;
    const int row = m * 16 + l15;
    const int f0 = s * 32 + quad * 8;
#pragma unroll
    for (int j = 0; j < 8; ++j) {
        const int f = f0 + j;
        float v = (row < NI && f < NF) ? alpha[(f * NI + row) * NN + n] : 0.f;
        r[j] = (__bf16)v;
    }
    return r;
}
__device__ __forceinline__ bf16x8 mk_wh_frag(const float* __restrict__ W,
        const float* __restrict__ h, int n, int tt, int s, int l15, int quad) {
    bf16x8 r;
    const int row = tt * 16 + l15;
    const int k0 = s * 32 + quad * 8;
#pragma unroll
    for (int j = 0; j < 8; ++j) {
        float v = W[n * ED * ED + row * ED + k0 + j] * h[n * ED + k0 + j];
        r[j] = (__bf16)v;
    }
    return r;
}

__global__ __launch_bounds__(256) void gif_mfma(
        const float* __restrict__ B0, const float* __restrict__ Bi,
        const unsigned short* __restrict__ whp, const unsigned short* __restrict__ alp,
        const float* __restrict__ W, const float* __restrict__ alpha,
        const float* __restrict__ h, int useWs, float* __restrict__ out) {
    const int q = blockIdx.x >> 8;
    const int b = blockIdx.x & 255;

    __shared__ __align__(16) unsigned short sBi[48 * PS];
    __shared__ __align__(16) unsigned short sBT[ED * PS];

    const int t = threadIdx.x;
    for (int idx = t; idx < 48 * PS; idx += 256) {
        int i = idx / PS, c = idx - i * PS;
        sBi[idx] = (i < NI && c < ED) ? f2bf(Bi[b * NI * ED + i * ED + c])
                                      : (unsigned short)0;
    }
    for (int idx = t; idx < ED * PS; idx += 256) {
        int D = idx / PS, c = idx - D * PS;
        sBT[idx] = (c < NF) ? f2bf(B0[b * NF * ED + c * ED + D])
                            : (unsigned short)0;
    }
    __syncthreads();

    const int lane = t & 63, w = t >> 6;
    const int quad = lane >> 4, l15 = lane & 15;
    const int fragoff = quad * 8;

    bf16x8 biA[3][2], b0B[4][2];
#pragma unroll
    for (int m = 0; m < 3; ++m)
#pragma unroll
        for (int s = 0; s < 2; ++s)
            biA[m][s] = ld_frag(&sBi[(m * 16 + l15) * PS + s * 32 + fragoff]);
#pragma unroll
    for (int tt = 0; tt < 4; ++tt)
#pragma unroll
        for (int s = 0; s < 2; ++s)
            b0B[tt][s] = ld_frag(&sBT[(tt * 16 + l15) * PS + s * 32 + fragoff]);

#pragma unroll
    for (int rep = 0; rep < 2; ++rep) {
        const int n = q * 8 + w + rep * 4;

        bf16x8 alA[3][2];
        if (useWs) {
#pragma unroll
            for (int m = 0; m < 3; ++m)
#pragma unroll
                for (int s = 0; s < 2; ++s)
                    alA[m][s] = ld_frag(&alp[n * AL_N + (m * 16 + l15) * PS + s * 32 + fragoff]);
        } else {
#pragma unroll
            for (int m = 0; m < 3; ++m)
#pragma unroll
                for (int s = 0; s < 2; ++s)
                    alA[m][s] = mk_al_frag(alpha, n, m, s, l15, quad);
        }

        float p[4];
#pragma unroll
        for (int tt = 0; tt < 4; ++tt) {
            bf16x8 whB2[2];
            if (useWs) {
                const unsigned short* wpp = &whp[n * WH_N + (tt * 16 + l15) * PS + fragoff];
                whB2[0] = ld_frag(wpp);
                whB2[1] = ld_frag(wpp + 32);
            } else {
                whB2[0] = mk_wh_frag(W, h, n, tt, 0, l15, quad);
                whB2[1] = mk_wh_frag(W, h, n, tt, 1, l15, quad);
            }
            float acc = 0.f;
#pragma unroll
            for (int m = 0; m < 3; ++m) {
                f32x4 z = {0.f, 0.f, 0.f, 0.f};
                f32x4 T = mfma16(biA[m][0], whB2[0], z);
                T = mfma16(biA[m][1], whB2[1], T);
                f32x4 G = mfma16(alA[m][0], b0B[tt][0], z);
                G = mfma16(alA[m][1], b0B[tt][1], G);
                acc += T[0] * G[0] + T[1] * G[1] + T[2] * G[2] + T[3] * G[3];
            }
            p[tt] = acc;
        }
#pragma unroll
        for (int tt = 0; tt < 4; ++tt) {
            p[tt] += __shfl_xor(p[tt], 16, 64);
            p[tt] += __shfl_xor(p[tt], 32, 64);
        }
        float v = (quad == 0) ? p[0] : (quad == 1) ? p[1] : (quad == 2) ? p[2] : p[3];
        out[(b * NN + n) * ED + lane] = v;
    }
}

// ==========================================================================
extern "C" void kernel_launch(void* const* d_in, const int* in_sizes, int n_in,
                              void* d_out, int out_size, void* d_ws, size_t ws_size,
                              hipStream_t stream) {
    const float* B0    = (const float*)d_in[0];  // (256,40,64)
    const float* Bi    = (const float*)d_in[1];  // (256,40,64)
    const float* W     = (const float*)d_in[2];  // (40,64,64)
    const float* alpha = (const float*)d_in[3];  // (40,40,40)
    const float* h     = (const float*)d_in[4];  // (40,64,1)
    float* out = (float*)d_out;                  // (256,40,64)

    const size_t need2 = (size_t)(NN * WHP_N + NN * ALP_N) * sizeof(unsigned short);
    if (ws_size >= need2) {
        unsigned short* whp = (unsigned short*)d_ws;
        unsigned short* alp = whp + (size_t)NN * WHP_N;
        gif_prep4<<<NN + NF, 256, 0, stream>>>(W, alpha, h, whp, alp);
        gif_main8<<<dim3(64, 10), 256, 0, stream>>>(B0, Bi, whp, alp, out);
        return;
    }

    const size_t need1 = (size_t)(NN * WH_N + NN * AL_N) * sizeof(unsigned short);
    const int useWs = (ws_size >= need1) ? 1 : 0;
    unsigned short* whp = (unsigned short*)d_ws;
    unsigned short* alp = whp + (size_t)NN * WH_N;
    if (useWs) {
        gif_prep<<<dim3(NN, 4), 256, 0, stream>>>(W, alpha, h, whp, alp);
    }
    gif_mfma<<<5 * NB, 256, 0, stream>>>(B0, Bi, whp, alp, W, alpha, h, useWs, out);
}